// Round 7
// baseline (35.325 us; speedup 1.0000x reference)
//
#include <hip/hip_runtime.h>
#include <hip/hip_fp16.h>

#define NPART 500000
#define MPART 450000
#define NBXC 1024
#define NBYC 1024
#define KROW 7                  // max bins/axis: w,h <= 6.0 -> span <= 7
#define NBLK_PART 1954          // ceil(500000/256)

// ---------------------------------------------------------------------------
// Kernel A: velocity field, vectorized 4 cells/thread along y.
// Field stored as __half2 {vx,vy} (4 MB -> L2-resident for the gathers).
// 1024 blocks -> partials[1024].
// ---------------------------------------------------------------------------
__global__ __launch_bounds__(256) void field_kernel(const float* __restrict__ pot,
                                                    const float* __restrict__ rho,
                                                    __half2* __restrict__ v,
                                                    float* __restrict__ partials) {
    const int idx = blockIdx.x * 256 + threadIdx.x;      // 0 .. 262143
    const int i  = idx >> 8;                             // row 0..1023
    const int j4 = (idx & 255) << 2;                     // col 0,4,..,1020

    const int ip = min(i + 1, NBXC - 1);
    const int im = max(i - 1, 0);
    const float sx = (ip - im == 2) ? 0.5f : 1.0f;

    const float4 c  = *reinterpret_cast<const float4*>(pot + i  * NBYC + j4);
    const float4 cu = *reinterpret_cast<const float4*>(pot + ip * NBYC + j4);
    const float4 cd = *reinterpret_cast<const float4*>(pot + im * NBYC + j4);
    const float  cl = pot[i * NBYC + max(j4 - 1, 0)];
    const float  cr = pot[i * NBYC + min(j4 + 4, NBYC - 1)];
    const float4 r4 = *reinterpret_cast<const float4*>(rho + i * NBYC + j4);

    const float vx0 = -(cu.x - cd.x) * sx;
    const float vx1 = -(cu.y - cd.y) * sx;
    const float vx2 = -(cu.z - cd.z) * sx;
    const float vx3 = -(cu.w - cd.w) * sx;

    const float vy0 = (j4 == 0)             ? -(c.y - c.x) : -(c.y - cl) * 0.5f;
    const float vy1 = -(c.z - c.x) * 0.5f;
    const float vy2 = -(c.w - c.y) * 0.5f;
    const float vy3 = (j4 + 3 == NBYC - 1)  ? -(c.w - c.z) : -(cr - c.z) * 0.5f;

    float4 st;
    st.x = __builtin_bit_cast(float, __floats2half2_rn(vx0, vy0));
    st.y = __builtin_bit_cast(float, __floats2half2_rn(vx1, vy1));
    st.z = __builtin_bit_cast(float, __floats2half2_rn(vx2, vy2));
    st.w = __builtin_bit_cast(float, __floats2half2_rn(vx3, vy3));
    *reinterpret_cast<float4*>(v + i * NBYC + j4) = st;

    float e = r4.x * (vx0 * vx0 + vy0 * vy0)
            + r4.y * (vx1 * vx1 + vy1 * vy1)
            + r4.z * (vx2 * vx2 + vy2 * vy2)
            + r4.w * (vx3 * vx3 + vy3 * vy3);
    #pragma unroll
    for (int off = 32; off > 0; off >>= 1) e += __shfl_down(e, off, 64);
    __shared__ float smem[4];
    const int lane = threadIdx.x & 63;
    const int wid  = threadIdx.x >> 6;
    if (lane == 0) smem[wid] = e;
    __syncthreads();
    if (threadIdx.x == 0) partials[blockIdx.x] = (smem[0] + smem[1]) + (smem[2] + smem[3]);
}

// ---------------------------------------------------------------------------
// Kernel C: per-particle gradient (blocks 0..1953) + energy reduction
// (block 1954). Window loop is branchless with clamped-repeat row addresses:
// rows past the active count re-load the last active row (L1 hit, weight 0),
// so all 7x(2..3) float4 loads issue as ONE clause -> one L2 stall/particle
// instead of 4-6 serialized ones, at ~unchanged L2 traffic (round-5 lesson).
// ---------------------------------------------------------------------------
__global__ __launch_bounds__(256) void particle_kernel(const float* __restrict__ pos,
                                                       const float* __restrict__ nsx,
                                                       const float* __restrict__ nsy,
                                                       const __half2* __restrict__ v,
                                                       const float* __restrict__ partials,
                                                       float* __restrict__ out) {
    __shared__ float smem[4];

    if (blockIdx.x == NBLK_PART) {      // ---- energy reduction block ----
        const int t = threadIdx.x;
        float e = (partials[t] + partials[t + 256]) + (partials[t + 512] + partials[t + 768]);
        #pragma unroll
        for (int off = 32; off > 0; off >>= 1) e += __shfl_down(e, off, 64);
        const int lane = t & 63;
        const int wid  = t >> 6;
        if (lane == 0) smem[wid] = e;
        __syncthreads();
        if (t == 0) out[0] = 0.5f * ((smem[0] + smem[1]) + (smem[2] + smem[3]));
        return;
    }

    const int i = blockIdx.x * 256 + threadIdx.x;
    if (i >= NPART) return;
    if (i >= MPART) {                   // zero pad regions [M:N), [N+M:2N)
        out[1 + i]         = 0.0f;
        out[1 + NPART + i] = 0.0f;
        return;
    }

    const float px = pos[i];
    const float py = pos[NPART + i];
    const float w  = nsx[i];
    const float h  = nsy[i];

    float gpx, gpy;
    const bool large = (w >= 1.0f) || (h >= 1.0f);
    if (!large) {
        int ix = min(max((int)floorf(px), 0), NBXC - 1);
        int iy = min(max((int)floorf(py), 0), NBYC - 1);
        const float wx = fminf(fmaxf(px - (float)ix, 0.0f), 1.0f);
        const float wy = fminf(fmaxf(py - (float)iy, 0.0f), 1.0f);
        const int ix1 = min(ix + 1, NBXC - 1);
        const int iy1 = min(iy + 1, NBYC - 1);
        const float2 f00 = __half22float2(v[ix  * NBYC + iy ]);
        const float2 f10 = __half22float2(v[ix1 * NBYC + iy ]);
        const float2 f01 = __half22float2(v[ix  * NBYC + iy1]);
        const float2 f11 = __half22float2(v[ix1 * NBYC + iy1]);
        const float w00 = (1.0f - wx) * (1.0f - wy);
        const float w10 = wx * (1.0f - wy);
        const float w01 = (1.0f - wx) * wy;
        const float w11 = wx * wy;
        gpx = w00 * f00.x + w10 * f10.x + w01 * f01.x + w11 * f11.x;
        gpy = w00 * f00.y + w10 * f10.y + w01 * f01.y + w11 * f11.y;
    } else {
        const float lx = px - 0.5f * w, rx = px + 0.5f * w;
        const float ly = py - 0.5f * h, ry = py + 0.5f * h;
        const int bminx = min(max((int)floorf(lx), 0), NBXC - 1);
        const int bmaxx = min(max((int)floorf(rx), 0), NBXC - 1);
        const int bminy = min(max((int)floorf(ly), 0), NBYC - 1);
        const int bmaxy = min(max((int)floorf(ry), 0), NBYC - 1);
        // 16B-aligned y-window start, clamped so all 12 cells stay in-row.
        const int by0 = min(bminy & ~3, NBYC - 12);
        const int nax = bmaxx - bminx;              // 0..6 active x-rows - 1
        const bool need3 = (bmaxy >= by0 + 8);      // 3rd float4 touched?

        // ---- load phase: all rows, control-independent (one clause) ----
        float4 q[KROW][3];
        #pragma unroll
        for (int k = 0; k < KROW; ++k) {
            const int bx = bminx + min(k, nax);     // repeat last active row
            const float4* rp = reinterpret_cast<const float4*>(v + bx * NBYC + by0);
            q[k][0] = rp[0];
            q[k][1] = rp[1];
            q[k][2] = need3 ? rp[2] : make_float4(0.0f, 0.0f, 0.0f, 0.0f);
        }

        // ---- weights ----
        float oy[12];
        #pragma unroll
        for (int k = 0; k < 12; ++k) {
            const int b = by0 + k;
            const float bl = (float)b;
            float ov = fminf(ry, bl + 1.0f) - fmaxf(ly, bl);
            oy[k] = (b <= bmaxy && ov > 0.0f) ? ov : 0.0f;
        }
        float ox[KROW];
        #pragma unroll
        for (int k = 0; k < KROW; ++k) {
            const int b = bminx + k;                // logical bin (not clamped row)
            const float bl = (float)b;
            float ov = fminf(rx, bl + 1.0f) - fmaxf(lx, bl);
            ox[k] = (b <= bmaxx && ov > 0.0f) ? ov : 0.0f;
        }

        // ---- accumulate ----
        float afx = 0.0f, afy = 0.0f;
        #pragma unroll
        for (int k = 0; k < KROW; ++k) {
            float sx = 0.0f, sy = 0.0f;
            #pragma unroll
            for (int r = 0; r < 3; ++r) {
                const float* qs = &q[k][r].x;
                #pragma unroll
                for (int e = 0; e < 4; ++e) {
                    const float2 f = __half22float2(__builtin_bit_cast(__half2, qs[e]));
                    sx += f.x * oy[r * 4 + e];
                    sy += f.y * oy[r * 4 + e];
                }
            }
            afx += sx * ox[k];
            afy += sy * ox[k];
        }
        const float inv = 1.0f / fmaxf(w * h, 1e-30f);
        gpx = afx * inv;
        gpy = afy * inv;
    }
    out[1 + i]         = gpx;
    out[1 + NPART + i] = gpy;
}

extern "C" void kernel_launch(void* const* d_in, const int* in_sizes, int n_in,
                              void* d_out, int out_size, void* d_ws, size_t ws_size,
                              hipStream_t stream) {
    const float* pos = (const float*)d_in[0];
    const float* pot = (const float*)d_in[1];
    const float* rho = (const float*)d_in[2];
    const float* nsx = (const float*)d_in[3];
    const float* nsy = (const float*)d_in[4];
    float* out = (float*)d_out;

    __half2* v      = (__half2*)d_ws;                                     // 4 MB
    float* partials = (float*)((char*)d_ws + (size_t)NBXC * NBYC * sizeof(__half2));

    field_kernel<<<(NBXC * NBYC / 4) / 256, 256, 0, stream>>>(pot, rho, v, partials);
    particle_kernel<<<NBLK_PART + 1, 256, 0, stream>>>(pos, nsx, nsy, v, partials, out);
}

// Round 8
// 31.812 us; speedup vs baseline: 1.1104x; 1.1104x over previous
//
#include <hip/hip_runtime.h>
#include <hip/hip_fp16.h>

#define NPART 500000
#define MPART 450000
#define NBXC 1024
#define NBYC 1024
#define KROW 7                  // w,h < 6.0 -> window spans at most 7 bins/axis
#define NBLK_PART 1954          // ceil(500000/256)

// ---------------------------------------------------------------------------
// Kernel A: velocity field, vectorized 4 cells/thread along y.
// Field stored as __half2 {vx,vy} (4 MB -> L2-resident for the gathers).
// 1024 blocks -> partials[1024].
// ---------------------------------------------------------------------------
__global__ __launch_bounds__(256) void field_kernel(const float* __restrict__ pot,
                                                    const float* __restrict__ rho,
                                                    __half2* __restrict__ v,
                                                    float* __restrict__ partials) {
    const int idx = blockIdx.x * 256 + threadIdx.x;      // 0 .. 262143
    const int i  = idx >> 8;                             // row 0..1023
    const int j4 = (idx & 255) << 2;                     // col 0,4,..,1020

    const int ip = min(i + 1, NBXC - 1);
    const int im = max(i - 1, 0);
    const float sx = (ip - im == 2) ? 0.5f : 1.0f;

    const float4 c  = *reinterpret_cast<const float4*>(pot + i  * NBYC + j4);
    const float4 cu = *reinterpret_cast<const float4*>(pot + ip * NBYC + j4);
    const float4 cd = *reinterpret_cast<const float4*>(pot + im * NBYC + j4);
    const float  cl = pot[i * NBYC + max(j4 - 1, 0)];
    const float  cr = pot[i * NBYC + min(j4 + 4, NBYC - 1)];
    const float4 r4 = *reinterpret_cast<const float4*>(rho + i * NBYC + j4);

    const float vx0 = -(cu.x - cd.x) * sx;
    const float vx1 = -(cu.y - cd.y) * sx;
    const float vx2 = -(cu.z - cd.z) * sx;
    const float vx3 = -(cu.w - cd.w) * sx;

    const float vy0 = (j4 == 0)             ? -(c.y - c.x) : -(c.y - cl) * 0.5f;
    const float vy1 = -(c.z - c.x) * 0.5f;
    const float vy2 = -(c.w - c.y) * 0.5f;
    const float vy3 = (j4 + 3 == NBYC - 1)  ? -(c.w - c.z) : -(cr - c.z) * 0.5f;

    float4 st;
    st.x = __builtin_bit_cast(float, __floats2half2_rn(vx0, vy0));
    st.y = __builtin_bit_cast(float, __floats2half2_rn(vx1, vy1));
    st.z = __builtin_bit_cast(float, __floats2half2_rn(vx2, vy2));
    st.w = __builtin_bit_cast(float, __floats2half2_rn(vx3, vy3));
    *reinterpret_cast<float4*>(v + i * NBYC + j4) = st;

    float e = r4.x * (vx0 * vx0 + vy0 * vy0)
            + r4.y * (vx1 * vx1 + vy1 * vy1)
            + r4.z * (vx2 * vx2 + vy2 * vy2)
            + r4.w * (vx3 * vx3 + vy3 * vy3);
    #pragma unroll
    for (int off = 32; off > 0; off >>= 1) e += __shfl_down(e, off, 64);
    __shared__ float smem[4];
    const int lane = threadIdx.x & 63;
    const int wid  = threadIdx.x >> 6;
    if (lane == 0) smem[wid] = e;
    __syncthreads();
    if (threadIdx.x == 0) partials[blockIdx.x] = (smem[0] + smem[1]) + (smem[2] + smem[3]);
}

// ---------------------------------------------------------------------------
// Kernel C: per-particle gradient (blocks 0..1953) + energy reduction
// (block 1954). Exec-masked loads only (round-5/7 lesson: unconditional
// gathers cost ~linearly in active-lane count). vs round 6:
//  - q1/q2 loads additionally masked on ncell (avg loads/row 3.0 -> ~1.9)
//  - 7 rows, processed as 3 pairs + 1 solo with loads-only branches, so two
//    rows' L2 round-trips overlap at only +6 float4 registers.
// ---------------------------------------------------------------------------
__global__ __launch_bounds__(256) void particle_kernel(const float* __restrict__ pos,
                                                       const float* __restrict__ nsx,
                                                       const float* __restrict__ nsy,
                                                       const __half2* __restrict__ v,
                                                       const float* __restrict__ partials,
                                                       float* __restrict__ out) {
    __shared__ float smem[4];

    if (blockIdx.x == NBLK_PART) {      // ---- energy reduction block ----
        const int t = threadIdx.x;
        float e = (partials[t] + partials[t + 256]) + (partials[t + 512] + partials[t + 768]);
        #pragma unroll
        for (int off = 32; off > 0; off >>= 1) e += __shfl_down(e, off, 64);
        const int lane = t & 63;
        const int wid  = t >> 6;
        if (lane == 0) smem[wid] = e;
        __syncthreads();
        if (t == 0) out[0] = 0.5f * ((smem[0] + smem[1]) + (smem[2] + smem[3]));
        return;
    }

    const int i = blockIdx.x * 256 + threadIdx.x;
    if (i >= NPART) return;
    if (i >= MPART) {                   // zero pad regions [M:N), [N+M:2N)
        out[1 + i]         = 0.0f;
        out[1 + NPART + i] = 0.0f;
        return;
    }

    const float px = pos[i];
    const float py = pos[NPART + i];
    const float w  = nsx[i];
    const float h  = nsy[i];

    float gpx, gpy;
    const bool large = (w >= 1.0f) || (h >= 1.0f);
    if (!large) {
        int ix = min(max((int)floorf(px), 0), NBXC - 1);
        int iy = min(max((int)floorf(py), 0), NBYC - 1);
        const float wx = fminf(fmaxf(px - (float)ix, 0.0f), 1.0f);
        const float wy = fminf(fmaxf(py - (float)iy, 0.0f), 1.0f);
        const int ix1 = min(ix + 1, NBXC - 1);
        const int iy1 = min(iy + 1, NBYC - 1);
        const float2 f00 = __half22float2(v[ix  * NBYC + iy ]);
        const float2 f10 = __half22float2(v[ix1 * NBYC + iy ]);
        const float2 f01 = __half22float2(v[ix  * NBYC + iy1]);
        const float2 f11 = __half22float2(v[ix1 * NBYC + iy1]);
        const float w00 = (1.0f - wx) * (1.0f - wy);
        const float w10 = wx * (1.0f - wy);
        const float w01 = (1.0f - wx) * wy;
        const float w11 = wx * wy;
        gpx = w00 * f00.x + w10 * f10.x + w01 * f01.x + w11 * f11.x;
        gpy = w00 * f00.y + w10 * f10.y + w01 * f01.y + w11 * f11.y;
    } else {
        const float lx = px - 0.5f * w, rx = px + 0.5f * w;
        const float ly = py - 0.5f * h, ry = py + 0.5f * h;
        const int bminx = min(max((int)floorf(lx), 0), NBXC - 1);
        const int bmaxx = min(max((int)floorf(rx), 0), NBXC - 1);
        const int bminy = min(max((int)floorf(ly), 0), NBYC - 1);
        const int bmaxy = min(max((int)floorf(ry), 0), NBYC - 1);
        // 16B-aligned y-window start, clamped so all 12 cells stay in-row.
        const int by0   = min(bminy & ~3, NBYC - 12);
        const int ncell = bmaxy - by0;              // last active cell index, 0..11

        float oy[12];
        #pragma unroll
        for (int k = 0; k < 12; ++k) {
            const int b = by0 + k;
            const float bl = (float)b;
            float ov = fminf(ry, bl + 1.0f) - fmaxf(ly, bl);
            oy[k] = (b <= bmaxy && ov > 0.0f) ? ov : 0.0f;
        }
        float ox[KROW];
        #pragma unroll
        for (int k = 0; k < KROW; ++k) {
            const int b = bminx + k;
            const float bl = (float)b;
            float ov = fminf(rx, bl + 1.0f) - fmaxf(lx, bl);
            ox[k] = (b <= bmaxx && ov > 0.0f) ? ov : 0.0f;
        }

        const float4 z = make_float4(0.0f, 0.0f, 0.0f, 0.0f);
        float afx = 0.0f, afy = 0.0f;

        auto rowptr = [&](int k) -> const float4* {
            const int bx = min(bminx + k, NBXC - 1);
            return reinterpret_cast<const float4*>(v + bx * NBYC + by0);
        };
        auto accum = [&](const float4& q0, const float4& q1, const float4& q2, float ov) {
            float sx = 0.0f, sy = 0.0f;
            const float* a0 = &q0.x;
            const float* a1 = &q1.x;
            const float* a2 = &q2.x;
            #pragma unroll
            for (int e = 0; e < 4; ++e) {
                const float2 f = __half22float2(__builtin_bit_cast(__half2, a0[e]));
                sx += f.x * oy[e];
                sy += f.y * oy[e];
            }
            #pragma unroll
            for (int e = 0; e < 4; ++e) {
                const float2 f = __half22float2(__builtin_bit_cast(__half2, a1[e]));
                sx += f.x * oy[4 + e];
                sy += f.y * oy[4 + e];
            }
            #pragma unroll
            for (int e = 0; e < 4; ++e) {
                const float2 f = __half22float2(__builtin_bit_cast(__half2, a2[e]));
                sx += f.x * oy[8 + e];
                sy += f.y * oy[8 + e];
            }
            afx += sx * ov;
            afy += sy * ov;
        };

        #pragma unroll
        for (int kp = 0; kp < 3; ++kp) {
            const int kA = 2 * kp, kB = 2 * kp + 1;
            const float ovA = ox[kA], ovB = ox[kB];
            float4 a0 = z, a1 = z, a2 = z, b0 = z, b1 = z, b2 = z;
            if (ovA > 0.0f) {                   // loads-only branch (exec-masked)
                const float4* rp = rowptr(kA);
                a0 = rp[0];
                if (ncell >= 4) a1 = rp[1];
                if (ncell >= 8) a2 = rp[2];
            }
            if (ovB > 0.0f) {                   // B's loads issue before A's FMAs stall
                const float4* rp = rowptr(kB);
                b0 = rp[0];
                if (ncell >= 4) b1 = rp[1];
                if (ncell >= 8) b2 = rp[2];
            }
            accum(a0, a1, a2, ovA);
            accum(b0, b1, b2, ovB);
        }
        {   // row 6 solo
            const float ov6 = ox[6];
            float4 a0 = z, a1 = z, a2 = z;
            if (ov6 > 0.0f) {
                const float4* rp = rowptr(6);
                a0 = rp[0];
                if (ncell >= 4) a1 = rp[1];
                if (ncell >= 8) a2 = rp[2];
            }
            accum(a0, a1, a2, ov6);
        }
        const float inv = 1.0f / fmaxf(w * h, 1e-30f);
        gpx = afx * inv;
        gpy = afy * inv;
    }
    out[1 + i]         = gpx;
    out[1 + NPART + i] = gpy;
}

extern "C" void kernel_launch(void* const* d_in, const int* in_sizes, int n_in,
                              void* d_out, int out_size, void* d_ws, size_t ws_size,
                              hipStream_t stream) {
    const float* pos = (const float*)d_in[0];
    const float* pot = (const float*)d_in[1];
    const float* rho = (const float*)d_in[2];
    const float* nsx = (const float*)d_in[3];
    const float* nsy = (const float*)d_in[4];
    float* out = (float*)d_out;

    __half2* v      = (__half2*)d_ws;                                     // 4 MB
    float* partials = (float*)((char*)d_ws + (size_t)NBXC * NBYC * sizeof(__half2));

    field_kernel<<<(NBXC * NBYC / 4) / 256, 256, 0, stream>>>(pot, rho, v, partials);
    particle_kernel<<<NBLK_PART + 1, 256, 0, stream>>>(pos, nsx, nsy, v, partials, out);
}